// Round 10
// baseline (387.348 us; speedup 1.0000x reference)
//
#include <hip/hip_runtime.h>
#include <hip/hip_fp16.h>
#include <cfloat>
#include <climits>

// argmin_k [ (||z||^2 + ||e_k||^2 - 2 z.e_k) * g ], g>0  ==  argmin_k [ 0.5||e_k||^2 - z.e_k ]
// MFMA fp16 3-term split filter (residuals pre-scaled x1024) -> best/secondbest ->
// flagged rows (gap < 1/512) exact f64 parallel rescan.
// R10: R3's proven kernel (32 rows/wave, 64 VGPR) + nsl=8 (8 blocks/CU) +
//      med3 second-best + SGPR-encoded argmin index. launch_bounds pins VGPR<=64.

typedef short  s16x8  __attribute__((ext_vector_type(8)));   // 8 fp16 operand frag
typedef float  f32x16 __attribute__((ext_vector_type(16)));  // 32x32 accumulator

static constexpr int N_ = 32768;
static constexpr int K_ = 8192;
static constexpr int D_ = 64;
static constexpr int NTILES = K_ / 32;             // 256 code-tiles
static constexpr int REC_SLOTS = 576;              // 16B slots per tile record (9216 B)
static constexpr size_t REC_BYTES = (size_t)NTILES * REC_SLOTS * 16;  // 2.25 MB
static constexpr float FLAG_MARGIN = 0.001953125f; // 1/512, ~10x worst-case fp16-filter error
static constexpr float RESID_SCALE = 1024.0f;
static constexpr float RESID_INV   = 0.0009765625f;

struct alignas(16) Part3 { float b1, b2; int i1, pad; };

__device__ __forceinline__ short f2h_s(float x) {
    __half h = __float2half(x);
    return (short)__half_as_short(h);
}

#define MFMA16(A, B, C) __builtin_amdgcn_mfma_f32_32x32x16_f16((A), (B), (C), 0, 0, 0)

// ---------------- prep: pack e into MFMA-frag-order tile records ----------------
// record layout (16B slots): [e1 f0..f3 : 4*64][sefrag : 64][e2 f0..f3 : 4*64]
// slot within frag f: h*32 + c  holds dims [16f + 8h, +8) of code c.  e2 scaled x1024.
__global__ void rq_prep(const float* __restrict__ emb, s16x8* __restrict__ recs,
                        int* __restrict__ counter)
{
    __shared__ double sp[32][8];
    const int tile = blockIdx.x;
    const int t = threadIdx.x;              // 256
    if (tile == 0 && t == 0) *counter = 0;  // replaces separate memset dispatch
    const int c = t >> 3, q = t & 7;
    const int f = q >> 1, h = q & 1;
    const float* src = emb + (size_t)(tile * 32 + c) * D_ + q * 8;
    float4 a = ((const float4*)src)[0];
    float4 b = ((const float4*)src)[1];
    float e[8] = {a.x, a.y, a.z, a.w, b.x, b.y, b.z, b.w};
    s16x8 u1, u2;
    double s = 0.0;
    #pragma unroll
    for (int j = 0; j < 8; ++j) {
        __half h1 = __float2half(e[j]);
        float r = e[j] - __half2float(h1);
        u1[j] = (short)__half_as_short(h1);
        u2[j] = f2h_s(r * RESID_SCALE);
        s = fma((double)e[j], (double)e[j], s);
    }
    const size_t rb = (size_t)tile * REC_SLOTS;
    recs[rb + f * 64 + h * 32 + c] = u1;
    recs[rb + 320 + f * 64 + h * 32 + c] = u2;
    sp[c][q] = s;
    __syncthreads();
    if (t < 32) {
        double se = 0.0;
        #pragma unroll
        for (int j = 0; j < 8; ++j) se += sp[t][j];
        se *= 0.5;
        float sf = (float)se;
        __half sh = __float2half(sf);
        float  sr = sf - __half2float(sh);
        s16x8 v;
        #pragma unroll
        for (int j = 0; j < 8; ++j) v[j] = 0;
        v[0] = (short)__half_as_short(sh);
        v[1] = f2h_s(sr);                       // unscaled lo (normal-range)
        recs[rb + 256 + t] = v;                 // h=0 slots
    } else if (t < 64) {
        s16x8 v;
        #pragma unroll
        for (int j = 0; j < 8; ++j) v[j] = 0;
        recs[rb + 256 + t] = v;                 // h=1 slots: zeros
    }
}

// ---------------- main: MFMA filter, best/secondbest per z-row ----------------
// R3 skeleton: 4 waves/block, 32 rows/wave, LDS dbuf, reg prefetch, 1 barrier/tile.
__global__ __launch_bounds__(256, 8)
void rq_main(const float* __restrict__ z,
             const s16x8* __restrict__ recs,
             Part3* __restrict__ parts,
             int tpb /* tiles per block */)
{
    __shared__ s16x8 lbuf[2][REC_SLOTS];        // 18432 B double buffer
    const int tid  = threadIdx.x;
    const int wave = tid >> 6, lane = tid & 63;
    const int col  = lane & 31, h = lane >> 5;
    const int slice = blockIdx.y;
    const int tile0 = slice * tpb;
    const int rowbase = blockIdx.x * 128 + wave * 32;
    const int zrow = rowbase + col;

    // B-frags: negated z, fp16 hi + (resid x1024). lane holds dims 16f+8h+j of its z-row.
    s16x8 zn1[4], zn2[4];
    #pragma unroll
    for (int f = 0; f < 4; ++f) {
        const float* src = z + (size_t)zrow * D_ + f * 16 + h * 8;
        float4 a = ((const float4*)src)[0];
        float4 b = ((const float4*)src)[1];
        float e[8] = {a.x, a.y, a.z, a.w, b.x, b.y, b.z, b.w};
        #pragma unroll
        for (int j = 0; j < 8; ++j) {
            float zn = -e[j];
            __half h1 = __float2half(zn);
            zn1[f][j] = (short)__half_as_short(h1);
            zn2[f][j] = f2h_s((zn - __half2float(h1)) * RESID_SCALE);
        }
    }
    // dummy B for the se-MFMA: B[k][col]=1 for k=0,1 (h==0 lanes); fp16 1.0 = 0x3C00
    s16x8 bse;
    #pragma unroll
    for (int j = 0; j < 8; ++j) bse[j] = 0;
    if (h == 0) { bse[0] = (short)0x3C00; bse[1] = (short)0x3C00; }

    // persistent zero C-operand
    f32x16 zacc;
    #pragma unroll
    for (int r = 0; r < 16; ++r) zacc[r] = 0.0f;

    // stage tile 0
    {
        const size_t gb = (size_t)tile0 * REC_SLOTS;
        lbuf[0][tid]       = recs[gb + tid];
        lbuf[0][256 + tid] = recs[gb + 256 + tid];
        if (tid < 64) lbuf[0][512 + tid] = recs[gb + 512 + tid];
    }
    __syncthreads();

    float b1 = FLT_MAX, b2 = FLT_MAX;
    int   i1 = INT_MAX;   // encoded (t<<4)|r  -- wave-uniform candidate values

    for (int t = 0; t < tpb; ++t) {
        const int cb = t & 1, nb = cb ^ 1;
        const bool pf = (t + 1 < tpb);
        s16x8 r0, r1, r2;
        if (pf) {   // issue next-tile global loads early (hide under MFMA)
            const size_t gb = (size_t)(tile0 + t + 1) * REC_SLOTS;
            r0 = recs[gb + tid];
            r1 = recs[gb + 256 + tid];
            if (tid < 64) r2 = recs[gb + 512 + tid];
        }

        // lane-linear frag reads (conflict-free)
        s16x8 ea[4], e2a[4], sea;
        #pragma unroll
        for (int f = 0; f < 4; ++f) ea[f]  = lbuf[cb][f * 64 + lane];
        sea = lbuf[cb][256 + lane];
        #pragma unroll
        for (int f = 0; f < 4; ++f) e2a[f] = lbuf[cb][320 + f * 64 + lane];

        // acc  = se - z1.e1      acc2 = -1024*(z1.e2 + z2.e1)   (z-frags pre-negated)
        f32x16 acc, acc2;
        acc  = MFMA16(sea,    bse,    zacc);
        acc2 = MFMA16(e2a[0], zn1[0], zacc);
        acc  = MFMA16(ea[0],  zn1[0], acc);
        acc2 = MFMA16(e2a[1], zn1[1], acc2);
        acc  = MFMA16(ea[1],  zn1[1], acc);
        acc2 = MFMA16(e2a[2], zn1[2], acc2);
        acc  = MFMA16(ea[2],  zn1[2], acc);
        acc2 = MFMA16(e2a[3], zn1[3], acc2);
        acc  = MFMA16(ea[3],  zn1[3], acc);
        acc2 = MFMA16(ea[0],  zn2[0], acc2);
        acc2 = MFMA16(ea[1],  zn2[1], acc2);
        acc2 = MFMA16(ea[2],  zn2[2], acc2);
        acc2 = MFMA16(ea[3],  zn2[3], acc2);

        // argmin: med3 secondbest + SGPR-encoded index (enc monotonic in code order)
        #pragma unroll
        for (int r = 0; r < 16; ++r) {
            float v = fmaf(acc2[r], RESID_INV, acc[r]);
            const int enc = (t << 4) | r;                  // wave-uniform -> SGPR
            b2 = __builtin_amdgcn_fmed3f(v, b1, b2);       // == fmin(b2,fmax(v,b1)), b1<=b2
            bool lt = v < b1;                              // strict: first occurrence wins
            i1 = lt ? enc : i1;
            b1 = fminf(b1, v);
        }

        if (pf) {
            lbuf[nb][tid]       = r0;
            lbuf[nb][256 + tid] = r1;
            if (tid < 64) lbuf[nb][512 + tid] = r2;
        }
        __syncthreads();
    }

    // decode enc -> absolute code index (uses this lane's h) BEFORE lane merge
    {
        const int tt = i1 >> 4, rr = i1 & 15;
        i1 = (tile0 + tt) * 32 + 4 * h + (rr & 3) + 8 * (rr >> 2);
    }

    // merge lane pair (l, l^32): covers interleaved code groups of same z-row
    float ob1 = __shfl_xor(b1, 32);
    float ob2 = __shfl_xor(b2, 32);
    int   oi1 = __shfl_xor(i1, 32);
    float nb2 = fminf(fminf(b2, ob2), fmaxf(b1, ob1));
    if (ob1 < b1 || (ob1 == b1 && oi1 < i1)) { b1 = ob1; i1 = oi1; }
    b2 = nb2;
    if (lane < 32) {
        Part3 p; p.b1 = b1; p.b2 = b2; p.i1 = i1; p.pad = 0;
        parts[(size_t)slice * N_ + (rowbase + lane)] = p;
    }
}

// ---------------- merge slices + flag close calls ----------------
__global__ void rq_merge(const Part3* __restrict__ parts,
                         const float* __restrict__ g,
                         int* __restrict__ out,
                         int* __restrict__ counter,
                         int* __restrict__ list,
                         int nsl, int maxf)
{
    int row = blockIdx.x * 256 + threadIdx.x;
    Part3 p = parts[row];
    float b1 = p.b1, b2 = p.b2; int i1 = p.i1;
    for (int s = 1; s < nsl; ++s) {
        Part3 q = parts[(size_t)s * N_ + row];
        float m2 = fminf(fminf(b2, q.b2), fmaxf(b1, q.b1));
        if (q.b1 < b1) { b1 = q.b1; i1 = q.i1; }   // strict <: earlier slice (lower k) wins
        b2 = m2;
    }
    if (g[row] == 0.0f) { out[row] = 0; return; }
    out[row] = i1;
    if (b2 - b1 < FLAG_MARGIN) {
        int idx = atomicAdd(counter, 1);
        if (idx < maxf) list[idx] = row;
    }
}

// ---------------- exact f64 parallel rescan: wave per (row, K/8-slice) ----------------
__global__ __launch_bounds__(256)
void rq_cleanup_part(const float* __restrict__ z,
                     const float* __restrict__ emb,
                     const int* __restrict__ counter,
                     const int* __restrict__ list,
                     double* __restrict__ vparts,
                     int* __restrict__ iparts,
                     int maxf)
{
    int cnt = *counter; if (cnt > maxf) cnt = maxf;
    const int jobs = cnt * 8;
    const int wid  = (blockIdx.x * 256 + threadIdx.x) >> 6;
    const int lane = threadIdx.x & 63;
    const int nw   = gridDim.x * 4;

    for (int j = wid; j < jobs; j += nw) {
        const int row = list[j >> 3];
        const int sl  = j & 7;
        float zr[64];
        {
            const float4* zp = reinterpret_cast<const float4*>(z + (size_t)row * D_);
            #pragma unroll
            for (int q = 0; q < 16; ++q) {
                float4 v = zp[q];
                zr[4*q] = v.x; zr[4*q+1] = v.y; zr[4*q+2] = v.z; zr[4*q+3] = v.w;
            }
        }
        double bv = DBL_MAX; int bi = INT_MAX;
        for (int i = 0; i < 16; ++i) {
            const int c = sl * 1024 + i * 64 + lane;
            const float4* ep = reinterpret_cast<const float4*>(emb + (size_t)c * D_);
            double sd0 = 0, sd1 = 0, sq0 = 0, sq1 = 0;
            #pragma unroll
            for (int q = 0; q < 16; ++q) {
                float4 ev = ep[q];
                sd0 = fma((double)ev.x, (double)zr[4*q+0], sd0);
                sq0 = fma((double)ev.x, (double)ev.x, sq0);
                sd1 = fma((double)ev.y, (double)zr[4*q+1], sd1);
                sq1 = fma((double)ev.y, (double)ev.y, sq1);
                sd0 = fma((double)ev.z, (double)zr[4*q+2], sd0);
                sq0 = fma((double)ev.z, (double)ev.z, sq0);
                sd1 = fma((double)ev.w, (double)zr[4*q+3], sd1);
                sq1 = fma((double)ev.w, (double)ev.w, sq1);
            }
            double v = 0.5 * (sq0 + sq1) - (sd0 + sd1);
            if (v < bv) { bv = v; bi = c; }     // ascending c per lane: strict < keeps first
        }
        #pragma unroll
        for (int m = 1; m < 64; m <<= 1) {
            double ov = __shfl_xor(bv, m);
            int    oi = __shfl_xor(bi, m);
            if (ov < bv || (ov == bv && oi < bi)) { bv = ov; bi = oi; }
        }
        if (lane == 0) { vparts[j] = bv; iparts[j] = bi; }
    }
}

__global__ void rq_cleanup_fin(const int* __restrict__ counter,
                               const int* __restrict__ list,
                               const double* __restrict__ vparts,
                               const int* __restrict__ iparts,
                               int* __restrict__ out, int maxf)
{
    int cnt = *counter; if (cnt > maxf) cnt = maxf;
    int j = blockIdx.x * 256 + threadIdx.x;
    if (j >= cnt) return;
    double bv = vparts[j * 8]; int bi = iparts[j * 8];
    #pragma unroll
    for (int s = 1; s < 8; ++s) {
        double v = vparts[j * 8 + s]; int i = iparts[j * 8 + s];
        if (v < bv || (v == bv && i < bi)) { bv = v; bi = i; }
    }
    out[list[j]] = bi;
}

// ---------------- fallback (proven R1 path, ws-independent) ----------------
__global__ __launch_bounds__(256, 4)
void rq_fallback(const float* __restrict__ z,
                 const float* __restrict__ emb,
                 const float* __restrict__ g,
                 int* __restrict__ out)
{
    __shared__ float  lds_e[64][64];
    __shared__ double lds_se[64];
    const int tid = threadIdx.x;
    const int row = blockIdx.x * 256 + tid;
    float zr[64];
    {
        const float4* zp = reinterpret_cast<const float4*>(z + (size_t)row * D_);
        #pragma unroll
        for (int j = 0; j < 16; ++j) {
            float4 v = zp[j];
            zr[4*j] = v.x; zr[4*j+1] = v.y; zr[4*j+2] = v.z; zr[4*j+3] = v.w;
        }
    }
    float best32 = FLT_MAX; double bestv = DBL_MAX; int bestidx = 0;
    for (int t = 0; t < K_; t += 64) {
        __syncthreads();
        {
            const float4* src = reinterpret_cast<const float4*>(emb + (size_t)t * D_);
            float4* dst = reinterpret_cast<float4*>(&lds_e[0][0]);
            #pragma unroll
            for (int j = 0; j < 4; ++j) dst[tid + j * 256] = src[tid + j * 256];
        }
        if (tid < 64) {
            const float* er = emb + (size_t)(t + tid) * D_;
            double s = 0;
            for (int d = 0; d < 64; ++d) s = fma((double)er[d], (double)er[d], s);
            lds_se[tid] = 0.5 * s;
        }
        __syncthreads();
        float cv0 = FLT_MAX, cv1 = FLT_MAX, cv2 = FLT_MAX;
        int ck0 = 0, ck1 = 0, ck2 = 0;
        for (int kk = 0; kk < 64; ++kk) {
            const float4* ep = reinterpret_cast<const float4*>(&lds_e[kk][0]);
            float a0 = 0, a1 = 0, a2 = 0, a3 = 0;
            #pragma unroll
            for (int j = 0; j < 16; ++j) {
                float4 e4 = ep[j];
                a0 = fmaf(zr[4*j], e4.x, a0);   a1 = fmaf(zr[4*j+1], e4.y, a1);
                a2 = fmaf(zr[4*j+2], e4.z, a2); a3 = fmaf(zr[4*j+3], e4.w, a3);
            }
            float val = (float)lds_se[kk] - ((a0 + a1) + (a2 + a3));
            if (val < best32 + 0.0625f) {
                cv2 = cv1; ck2 = ck1; cv1 = cv0; ck1 = ck0;
                cv0 = val; ck0 = kk;
                best32 = fminf(best32, val);
            }
        }
        const float thr = best32 + 0.0625f;
        #pragma unroll
        for (int r = 0; r < 3; ++r) {
            float cv = (r == 0) ? cv2 : (r == 1) ? cv1 : cv0;
            int   ck = (r == 0) ? ck2 : (r == 1) ? ck1 : ck0;
            if (cv < thr) {
                const float4* ep = reinterpret_cast<const float4*>(&lds_e[ck][0]);
                double s0 = 0, s1 = 0, s2 = 0, s3 = 0;
                #pragma unroll
                for (int j = 0; j < 16; ++j) {
                    float4 e4 = ep[j];
                    s0 = fma((double)zr[4*j],   (double)e4.x, s0);
                    s1 = fma((double)zr[4*j+1], (double)e4.y, s1);
                    s2 = fma((double)zr[4*j+2], (double)e4.z, s2);
                    s3 = fma((double)zr[4*j+3], (double)e4.w, s3);
                }
                double vd = lds_se[ck] - ((s0 + s1) + (s2 + s3));
                int kidx = t + ck;
                if (vd < bestv) { bestv = vd; bestidx = kidx; }
                else if (vd == bestv && kidx < bestidx) bestidx = kidx;
            }
        }
    }
    out[row] = (g[row] == 0.0f) ? 0 : bestidx;
}

extern "C" void kernel_launch(void* const* d_in, const int* in_sizes, int n_in,
                              void* d_out, int out_size, void* d_ws, size_t ws_size,
                              hipStream_t stream)
{
    const float* z   = (const float*)d_in[0];
    const float* g   = (const float*)d_in[1];
    const float* emb = (const float*)d_in[2];
    int* out = (int*)d_out;

    auto need = [&](int s, int mf) {
        return REC_BYTES + (size_t)s * N_ * sizeof(Part3) + 64
             + (size_t)mf * 4 + (size_t)mf * 8 * 8 + (size_t)mf * 8 * 4;
    };
    int nsl = 0, maxf = 0;
    const int nsls[4]  = {8, 4, 2, 1};
    const int maxfs[2] = {16384, 2048};
    for (int a = 0; a < 4 && !nsl; ++a)
        for (int b = 0; b < 2; ++b)
            if (need(nsls[a], maxfs[b]) <= ws_size) { nsl = nsls[a]; maxf = maxfs[b]; break; }

    if (!nsl) {
        rq_fallback<<<N_ / 256, 256, 0, stream>>>(z, emb, g, out);
        return;
    }

    char* w = (char*)d_ws;
    s16x8*  recs    = (s16x8*)w;                              w += REC_BYTES;
    Part3*  parts   = (Part3*)w;                              w += (size_t)nsl * N_ * sizeof(Part3);
    int*    counter = (int*)w;                                w += 64;
    int*    list    = (int*)w;                                w += (size_t)maxf * 4;
    double* vparts  = (double*)w;                             w += (size_t)maxf * 8 * 8;
    int*    iparts  = (int*)w;

    rq_prep<<<NTILES, 256, 0, stream>>>(emb, recs, counter);
    rq_main<<<dim3(N_ / 128, nsl), 256, 0, stream>>>(z, recs, parts, NTILES / nsl);
    rq_merge<<<N_ / 256, 256, 0, stream>>>(parts, g, out, counter, list, nsl, maxf);
    rq_cleanup_part<<<512, 256, 0, stream>>>(z, emb, counter, list, vparts, iparts, maxf);
    rq_cleanup_fin<<<128, 256, 0, stream>>>(counter, list, vparts, iparts, out, maxf);
}

// Round 11
// 159.871 us; speedup vs baseline: 2.4229x; 2.4229x over previous
//
#include <hip/hip_runtime.h>
#include <hip/hip_fp16.h>
#include <cfloat>
#include <climits>

// argmin_k [ (||z||^2 + ||e_k||^2 - 2 z.e_k) * g ], g>0  ==  argmin_k [ 0.5||e_k||^2 - z.e_k ]
// MFMA fp16 3-term split filter (residuals pre-scaled x1024) -> best/secondbest ->
// flagged rows (gap < 1/512) exact f64 parallel rescan.
// R11: R3 skeleton + async global_load_lds staging (m97 lever: no reg round-trip,
//      loads in flight across the whole tile's compute) + med3/enc argmin. nsl=8.

typedef short  s16x8  __attribute__((ext_vector_type(8)));   // 8 fp16 operand frag
typedef float  f32x16 __attribute__((ext_vector_type(16)));  // 32x32 accumulator

static constexpr int N_ = 32768;
static constexpr int K_ = 8192;
static constexpr int D_ = 64;
static constexpr int NTILES = K_ / 32;             // 256 code-tiles
static constexpr int REC_SLOTS = 576;              // 16B slots per tile record (9216 B)
static constexpr size_t REC_BYTES = (size_t)NTILES * REC_SLOTS * 16;  // 2.25 MB
static constexpr float FLAG_MARGIN = 0.001953125f; // 1/512, ~10x worst-case fp16-filter error
static constexpr float RESID_SCALE = 1024.0f;
static constexpr float RESID_INV   = 0.0009765625f;

struct alignas(16) Part3 { float b1, b2; int i1, pad; };

__device__ __forceinline__ short f2h_s(float x) {
    __half h = __float2half(x);
    return (short)__half_as_short(h);
}

#define MFMA16(A, B, C) __builtin_amdgcn_mfma_f32_32x32x16_f16((A), (B), (C), 0, 0, 0)

// async global -> LDS, 16B per lane; LDS base must be wave-uniform.
typedef __attribute__((address_space(1))) const void* gas_ptr;
typedef __attribute__((address_space(3))) void* las_ptr;
__device__ __forceinline__ void g2l(const s16x8* g, s16x8* l) {
    __builtin_amdgcn_global_load_lds((gas_ptr)g, (las_ptr)l, 16, 0, 0);
}

// ---------------- prep: pack e into MFMA-frag-order tile records ----------------
// record layout (16B slots): [e1 f0..f3 : 4*64][sefrag : 64][e2 f0..f3 : 4*64]
// slot within frag f: h*32 + c  holds dims [16f + 8h, +8) of code c.  e2 scaled x1024.
__global__ void rq_prep(const float* __restrict__ emb, s16x8* __restrict__ recs,
                        int* __restrict__ counter)
{
    __shared__ double sp[32][8];
    const int tile = blockIdx.x;
    const int t = threadIdx.x;              // 256
    if (tile == 0 && t == 0) *counter = 0;  // replaces separate memset dispatch
    const int c = t >> 3, q = t & 7;
    const int f = q >> 1, h = q & 1;
    const float* src = emb + (size_t)(tile * 32 + c) * D_ + q * 8;
    float4 a = ((const float4*)src)[0];
    float4 b = ((const float4*)src)[1];
    float e[8] = {a.x, a.y, a.z, a.w, b.x, b.y, b.z, b.w};
    s16x8 u1, u2;
    double s = 0.0;
    #pragma unroll
    for (int j = 0; j < 8; ++j) {
        __half h1 = __float2half(e[j]);
        float r = e[j] - __half2float(h1);
        u1[j] = (short)__half_as_short(h1);
        u2[j] = f2h_s(r * RESID_SCALE);
        s = fma((double)e[j], (double)e[j], s);
    }
    const size_t rb = (size_t)tile * REC_SLOTS;
    recs[rb + f * 64 + h * 32 + c] = u1;
    recs[rb + 320 + f * 64 + h * 32 + c] = u2;
    sp[c][q] = s;
    __syncthreads();
    if (t < 32) {
        double se = 0.0;
        #pragma unroll
        for (int j = 0; j < 8; ++j) se += sp[t][j];
        se *= 0.5;
        float sf = (float)se;
        __half sh = __float2half(sf);
        float  sr = sf - __half2float(sh);
        s16x8 v;
        #pragma unroll
        for (int j = 0; j < 8; ++j) v[j] = 0;
        v[0] = (short)__half_as_short(sh);
        v[1] = f2h_s(sr);                       // unscaled lo (normal-range)
        recs[rb + 256 + t] = v;                 // h=0 slots
    } else if (t < 64) {
        s16x8 v;
        #pragma unroll
        for (int j = 0; j < 8; ++j) v[j] = 0;
        recs[rb + 256 + t] = v;                 // h=1 slots: zeros
    }
}

// ---------------- main: MFMA filter, best/secondbest per z-row ----------------
// R3 skeleton: 4 waves/block, 32 rows/wave, LDS dbuf, 1 barrier/tile.
// Staging via async global_load_lds (lane-linear, both sides unswizzled).
__global__ __launch_bounds__(256)
void rq_main(const float* __restrict__ z,
             const s16x8* __restrict__ recs,
             Part3* __restrict__ parts,
             int tpb /* tiles per block */)
{
    __shared__ s16x8 lbuf[2][REC_SLOTS];        // 18432 B double buffer
    const int tid  = threadIdx.x;
    const int wave = tid >> 6, lane = tid & 63;
    const int col  = lane & 31, h = lane >> 5;
    const int slice = blockIdx.y;
    const int tile0 = slice * tpb;
    const int rowbase = blockIdx.x * 128 + wave * 32;
    const int zrow = rowbase + col;

    // B-frags: negated z, fp16 hi + (resid x1024). lane holds dims 16f+8h+j of its z-row.
    s16x8 zn1[4], zn2[4];
    #pragma unroll
    for (int f = 0; f < 4; ++f) {
        const float* src = z + (size_t)zrow * D_ + f * 16 + h * 8;
        float4 a = ((const float4*)src)[0];
        float4 b = ((const float4*)src)[1];
        float e[8] = {a.x, a.y, a.z, a.w, b.x, b.y, b.z, b.w};
        #pragma unroll
        for (int j = 0; j < 8; ++j) {
            float zn = -e[j];
            __half h1 = __float2half(zn);
            zn1[f][j] = (short)__half_as_short(h1);
            zn2[f][j] = f2h_s((zn - __half2float(h1)) * RESID_SCALE);
        }
    }
    // dummy B for the se-MFMA: B[k][col]=1 for k=0,1 (h==0 lanes); fp16 1.0 = 0x3C00
    s16x8 bse;
    #pragma unroll
    for (int j = 0; j < 8; ++j) bse[j] = 0;
    if (h == 0) { bse[0] = (short)0x3C00; bse[1] = (short)0x3C00; }

    // persistent zero C-operand
    f32x16 zacc;
    #pragma unroll
    for (int r = 0; r < 16; ++r) zacc[r] = 0.0f;

    // async staging: each wave covers its 64-slot stripes; wave0 takes the tail 64.
    #define STAGE(BUF, TT) do {                                             \
        const s16x8* gb_ = recs + (size_t)(TT) * REC_SLOTS;                 \
        s16x8* lb_ = &lbuf[(BUF)][0];                                       \
        g2l(gb_ + wave * 64 + lane,       lb_ + wave * 64);                 \
        g2l(gb_ + 256 + wave * 64 + lane, lb_ + 256 + wave * 64);           \
        if (wave == 0) g2l(gb_ + 512 + lane, lb_ + 512);                    \
    } while (0)

    // stage tile 0
    STAGE(0, tile0);
    asm volatile("s_waitcnt vmcnt(0)" ::: "memory");
    __syncthreads();

    float b1 = FLT_MAX, b2 = FLT_MAX;
    int   i1 = INT_MAX;   // encoded (t<<4)|r, wave-uniform candidates -> SGPR cndmask

    for (int t = 0; t < tpb; ++t) {
        const int cb = t & 1, nb = cb ^ 1;
        if (t + 1 < tpb) STAGE(nb, tile0 + t + 1);   // async, in flight during compute

        // lane-linear frag reads (conflict-free)
        s16x8 ea[4], e2a[4], sea;
        #pragma unroll
        for (int f = 0; f < 4; ++f) ea[f]  = lbuf[cb][f * 64 + lane];
        sea = lbuf[cb][256 + lane];
        #pragma unroll
        for (int f = 0; f < 4; ++f) e2a[f] = lbuf[cb][320 + f * 64 + lane];

        // acc  = se - z1.e1      acc2 = -1024*(z1.e2 + z2.e1)   (z-frags pre-negated)
        f32x16 acc, acc2;
        acc  = MFMA16(sea,    bse,    zacc);
        acc2 = MFMA16(e2a[0], zn1[0], zacc);
        acc  = MFMA16(ea[0],  zn1[0], acc);
        acc2 = MFMA16(e2a[1], zn1[1], acc2);
        acc  = MFMA16(ea[1],  zn1[1], acc);
        acc2 = MFMA16(e2a[2], zn1[2], acc2);
        acc  = MFMA16(ea[2],  zn1[2], acc);
        acc2 = MFMA16(e2a[3], zn1[3], acc2);
        acc  = MFMA16(ea[3],  zn1[3], acc);
        acc2 = MFMA16(ea[0],  zn2[0], acc2);
        acc2 = MFMA16(ea[1],  zn2[1], acc2);
        acc2 = MFMA16(ea[2],  zn2[2], acc2);
        acc2 = MFMA16(ea[3],  zn2[3], acc2);

        // argmin: med3 secondbest + SGPR-encoded index (enc monotonic in code order)
        #pragma unroll
        for (int r = 0; r < 16; ++r) {
            float v = fmaf(acc2[r], RESID_INV, acc[r]);
            const int enc = (t << 4) | r;                  // wave-uniform
            b2 = __builtin_amdgcn_fmed3f(v, b1, b2);       // == fmin(b2, fmax(v, b1))
            bool lt = v < b1;                              // strict: first occurrence wins
            i1 = lt ? enc : i1;
            b1 = fminf(b1, v);
        }

        asm volatile("s_waitcnt vmcnt(0)" ::: "memory");   // drain staging into nb
        __syncthreads();                                    // all waves done reading cb
    }
    #undef STAGE

    // decode enc -> absolute code index (uses this lane's h) BEFORE lane merge
    {
        const int tt = i1 >> 4, rr = i1 & 15;
        i1 = (tile0 + tt) * 32 + 4 * h + (rr & 3) + 8 * (rr >> 2);
    }

    // merge lane pair (l, l^32): covers interleaved code groups of same z-row
    float ob1 = __shfl_xor(b1, 32);
    float ob2 = __shfl_xor(b2, 32);
    int   oi1 = __shfl_xor(i1, 32);
    float nb2 = fminf(fminf(b2, ob2), fmaxf(b1, ob1));
    if (ob1 < b1 || (ob1 == b1 && oi1 < i1)) { b1 = ob1; i1 = oi1; }
    b2 = nb2;
    if (lane < 32) {
        Part3 p; p.b1 = b1; p.b2 = b2; p.i1 = i1; p.pad = 0;
        parts[(size_t)slice * N_ + (rowbase + lane)] = p;
    }
}

// ---------------- merge slices + flag close calls ----------------
__global__ void rq_merge(const Part3* __restrict__ parts,
                         const float* __restrict__ g,
                         int* __restrict__ out,
                         int* __restrict__ counter,
                         int* __restrict__ list,
                         int nsl, int maxf)
{
    int row = blockIdx.x * 256 + threadIdx.x;
    Part3 p = parts[row];
    float b1 = p.b1, b2 = p.b2; int i1 = p.i1;
    for (int s = 1; s < nsl; ++s) {
        Part3 q = parts[(size_t)s * N_ + row];
        float m2 = fminf(fminf(b2, q.b2), fmaxf(b1, q.b1));
        if (q.b1 < b1) { b1 = q.b1; i1 = q.i1; }   // strict <: earlier slice (lower k) wins
        b2 = m2;
    }
    if (g[row] == 0.0f) { out[row] = 0; return; }
    out[row] = i1;
    if (b2 - b1 < FLAG_MARGIN) {
        int idx = atomicAdd(counter, 1);
        if (idx < maxf) list[idx] = row;
    }
}

// ---------------- exact f64 parallel rescan: wave per (row, K/8-slice) ----------------
__global__ __launch_bounds__(256)
void rq_cleanup_part(const float* __restrict__ z,
                     const float* __restrict__ emb,
                     const int* __restrict__ counter,
                     const int* __restrict__ list,
                     double* __restrict__ vparts,
                     int* __restrict__ iparts,
                     int maxf)
{
    int cnt = *counter; if (cnt > maxf) cnt = maxf;
    const int jobs = cnt * 8;
    const int wid  = (blockIdx.x * 256 + threadIdx.x) >> 6;
    const int lane = threadIdx.x & 63;
    const int nw   = gridDim.x * 4;

    for (int j = wid; j < jobs; j += nw) {
        const int row = list[j >> 3];
        const int sl  = j & 7;
        float zr[64];
        {
            const float4* zp = reinterpret_cast<const float4*>(z + (size_t)row * D_);
            #pragma unroll
            for (int q = 0; q < 16; ++q) {
                float4 v = zp[q];
                zr[4*q] = v.x; zr[4*q+1] = v.y; zr[4*q+2] = v.z; zr[4*q+3] = v.w;
            }
        }
        double bv = DBL_MAX; int bi = INT_MAX;
        for (int i = 0; i < 16; ++i) {
            const int c = sl * 1024 + i * 64 + lane;
            const float4* ep = reinterpret_cast<const float4*>(emb + (size_t)c * D_);
            double sd0 = 0, sd1 = 0, sq0 = 0, sq1 = 0;
            #pragma unroll
            for (int q = 0; q < 16; ++q) {
                float4 ev = ep[q];
                sd0 = fma((double)ev.x, (double)zr[4*q+0], sd0);
                sq0 = fma((double)ev.x, (double)ev.x, sq0);
                sd1 = fma((double)ev.y, (double)zr[4*q+1], sd1);
                sq1 = fma((double)ev.y, (double)ev.y, sq1);
                sd0 = fma((double)ev.z, (double)zr[4*q+2], sd0);
                sq0 = fma((double)ev.z, (double)ev.z, sq0);
                sd1 = fma((double)ev.w, (double)zr[4*q+3], sd1);
                sq1 = fma((double)ev.w, (double)ev.w, sq1);
            }
            double v = 0.5 * (sq0 + sq1) - (sd0 + sd1);
            if (v < bv) { bv = v; bi = c; }     // ascending c per lane: strict < keeps first
        }
        #pragma unroll
        for (int m = 1; m < 64; m <<= 1) {
            double ov = __shfl_xor(bv, m);
            int    oi = __shfl_xor(bi, m);
            if (ov < bv || (ov == bv && oi < bi)) { bv = ov; bi = oi; }
        }
        if (lane == 0) { vparts[j] = bv; iparts[j] = bi; }
    }
}

__global__ void rq_cleanup_fin(const int* __restrict__ counter,
                               const int* __restrict__ list,
                               const double* __restrict__ vparts,
                               const int* __restrict__ iparts,
                               int* __restrict__ out, int maxf)
{
    int cnt = *counter; if (cnt > maxf) cnt = maxf;
    int j = blockIdx.x * 256 + threadIdx.x;
    if (j >= cnt) return;
    double bv = vparts[j * 8]; int bi = iparts[j * 8];
    #pragma unroll
    for (int s = 1; s < 8; ++s) {
        double v = vparts[j * 8 + s]; int i = iparts[j * 8 + s];
        if (v < bv || (v == bv && i < bi)) { bv = v; bi = i; }
    }
    out[list[j]] = bi;
}

// ---------------- fallback (proven R1 path, ws-independent) ----------------
__global__ __launch_bounds__(256, 4)
void rq_fallback(const float* __restrict__ z,
                 const float* __restrict__ emb,
                 const float* __restrict__ g,
                 int* __restrict__ out)
{
    __shared__ float  lds_e[64][64];
    __shared__ double lds_se[64];
    const int tid = threadIdx.x;
    const int row = blockIdx.x * 256 + tid;
    float zr[64];
    {
        const float4* zp = reinterpret_cast<const float4*>(z + (size_t)row * D_);
        #pragma unroll
        for (int j = 0; j < 16; ++j) {
            float4 v = zp[j];
            zr[4*j] = v.x; zr[4*j+1] = v.y; zr[4*j+2] = v.z; zr[4*j+3] = v.w;
        }
    }
    float best32 = FLT_MAX; double bestv = DBL_MAX; int bestidx = 0;
    for (int t = 0; t < K_; t += 64) {
        __syncthreads();
        {
            const float4* src = reinterpret_cast<const float4*>(emb + (size_t)t * D_);
            float4* dst = reinterpret_cast<float4*>(&lds_e[0][0]);
            #pragma unroll
            for (int j = 0; j < 4; ++j) dst[tid + j * 256] = src[tid + j * 256];
        }
        if (tid < 64) {
            const float* er = emb + (size_t)(t + tid) * D_;
            double s = 0;
            for (int d = 0; d < 64; ++d) s = fma((double)er[d], (double)er[d], s);
            lds_se[tid] = 0.5 * s;
        }
        __syncthreads();
        float cv0 = FLT_MAX, cv1 = FLT_MAX, cv2 = FLT_MAX;
        int ck0 = 0, ck1 = 0, ck2 = 0;
        for (int kk = 0; kk < 64; ++kk) {
            const float4* ep = reinterpret_cast<const float4*>(&lds_e[kk][0]);
            float a0 = 0, a1 = 0, a2 = 0, a3 = 0;
            #pragma unroll
            for (int j = 0; j < 16; ++j) {
                float4 e4 = ep[j];
                a0 = fmaf(zr[4*j], e4.x, a0);   a1 = fmaf(zr[4*j+1], e4.y, a1);
                a2 = fmaf(zr[4*j+2], e4.z, a2); a3 = fmaf(zr[4*j+3], e4.w, a3);
            }
            float val = (float)lds_se[kk] - ((a0 + a1) + (a2 + a3));
            if (val < best32 + 0.0625f) {
                cv2 = cv1; ck2 = ck1; cv1 = cv0; ck1 = ck0;
                cv0 = val; ck0 = kk;
                best32 = fminf(best32, val);
            }
        }
        const float thr = best32 + 0.0625f;
        #pragma unroll
        for (int r = 0; r < 3; ++r) {
            float cv = (r == 0) ? cv2 : (r == 1) ? cv1 : cv0;
            int   ck = (r == 0) ? ck2 : (r == 1) ? ck1 : ck0;
            if (cv < thr) {
                const float4* ep = reinterpret_cast<const float4*>(&lds_e[ck][0]);
                double s0 = 0, s1 = 0, s2 = 0, s3 = 0;
                #pragma unroll
                for (int j = 0; j < 16; ++j) {
                    float4 e4 = ep[j];
                    s0 = fma((double)zr[4*j],   (double)e4.x, s0);
                    s1 = fma((double)zr[4*j+1], (double)e4.y, s1);
                    s2 = fma((double)zr[4*j+2], (double)e4.z, s2);
                    s3 = fma((double)zr[4*j+3], (double)e4.w, s3);
                }
                double vd = lds_se[ck] - ((s0 + s1) + (s2 + s3));
                int kidx = t + ck;
                if (vd < bestv) { bestv = vd; bestidx = kidx; }
                else if (vd == bestv && kidx < bestidx) bestidx = kidx;
            }
        }
    }
    out[row] = (g[row] == 0.0f) ? 0 : bestidx;
}

extern "C" void kernel_launch(void* const* d_in, const int* in_sizes, int n_in,
                              void* d_out, int out_size, void* d_ws, size_t ws_size,
                              hipStream_t stream)
{
    const float* z   = (const float*)d_in[0];
    const float* g   = (const float*)d_in[1];
    const float* emb = (const float*)d_in[2];
    int* out = (int*)d_out;

    auto need = [&](int s, int mf) {
        return REC_BYTES + (size_t)s * N_ * sizeof(Part3) + 64
             + (size_t)mf * 4 + (size_t)mf * 8 * 8 + (size_t)mf * 8 * 4;
    };
    int nsl = 0, maxf = 0;
    const int nsls[4]  = {8, 4, 2, 1};
    const int maxfs[2] = {16384, 2048};
    for (int a = 0; a < 4 && !nsl; ++a)
        for (int b = 0; b < 2; ++b)
            if (need(nsls[a], maxfs[b]) <= ws_size) { nsl = nsls[a]; maxf = maxfs[b]; break; }

    if (!nsl) {
        rq_fallback<<<N_ / 256, 256, 0, stream>>>(z, emb, g, out);
        return;
    }

    char* w = (char*)d_ws;
    s16x8*  recs    = (s16x8*)w;                              w += REC_BYTES;
    Part3*  parts   = (Part3*)w;                              w += (size_t)nsl * N_ * sizeof(Part3);
    int*    counter = (int*)w;                                w += 64;
    int*    list    = (int*)w;                                w += (size_t)maxf * 4;
    double* vparts  = (double*)w;                             w += (size_t)maxf * 8 * 8;
    int*    iparts  = (int*)w;

    rq_prep<<<NTILES, 256, 0, stream>>>(emb, recs, counter);
    rq_main<<<dim3(N_ / 128, nsl), 256, 0, stream>>>(z, recs, parts, NTILES / nsl);
    rq_merge<<<N_ / 256, 256, 0, stream>>>(parts, g, out, counter, list, nsl, maxf);
    rq_cleanup_part<<<512, 256, 0, stream>>>(z, emb, counter, list, vparts, iparts, maxf);
    rq_cleanup_fin<<<128, 256, 0, stream>>>(counter, list, vparts, iparts, out, maxf);
}